// Round 7
// baseline (516.001 us; speedup 1.0000x reference)
//
#include <hip/hip_runtime.h>
#include <math.h>
#include <stdint.h>

#define BB 16
#define TT 512
#define CC 1024
#define HH 16
#define HD 64
#define NT (BB*TT)   // 8192 rows

typedef __bf16 bf16x8 __attribute__((ext_vector_type(8)));
typedef float f32x4 __attribute__((ext_vector_type(4)));

__device__ __forceinline__ unsigned short f2bf(float x) {
    union { float f; unsigned u; } v; v.f = x;
    unsigned r = v.u + 0x7fffu + ((v.u >> 16) & 1u);
    return (unsigned short)(r >> 16);
}

__device__ __forceinline__ void gload_lds16(const void* g, void* l) {
    __builtin_amdgcn_global_load_lds((const __attribute__((address_space(1))) uint32_t*)g,
                                     (__attribute__((address_space(3))) uint32_t*)l, 16, 0, 0);
}

// ---------------- weight transpose+convert: in[K,N] fp32 -> out[N,K] bf16 ----------------
__global__ __launch_bounds__(256) void tcvt_kernel(const float* __restrict__ in,
                                                   unsigned short* __restrict__ out,
                                                   int K, int N) {
    __shared__ float Tt[32][33];
    int n0 = blockIdx.x * 32, k0 = blockIdx.y * 32;
    int t = threadIdx.x;
#pragma unroll
    for (int i = 0; i < 4; i++) {
        int idx = i * 256 + t; int r = idx >> 5, c = idx & 31;
        Tt[r][c] = in[(size_t)(k0 + r) * N + n0 + c];
    }
    __syncthreads();
#pragma unroll
    for (int i = 0; i < 4; i++) {
        int idx = i * 256 + t; int r = idx >> 5, c = idx & 31; // r=n-local, c=k-local
        out[(size_t)(n0 + r) * K + k0 + c] = f2bf(Tt[c][r]);
    }
}

// ---------------- LayerNorm -> bf16 out ----------------
__global__ __launch_bounds__(256) void ln_kernel(const float* __restrict__ x,
                                                 const float* __restrict__ g,
                                                 const float* __restrict__ b,
                                                 unsigned short* __restrict__ out) {
    int row = blockIdx.x;
    const float* xr = x + (size_t)row * CC;
    unsigned short* orow = out + (size_t)row * CC;
    int tid = threadIdx.x;
    float v[4];
    float lsum = 0.f, lsq = 0.f;
#pragma unroll
    for (int i = 0; i < 4; i++) {
        v[i] = xr[tid + 256 * i];
        lsum += v[i];
        lsq  += v[i] * v[i];
    }
    __shared__ float ssum[4], ssq[4];
#pragma unroll
    for (int o = 32; o > 0; o >>= 1) {
        lsum += __shfl_down(lsum, o);
        lsq  += __shfl_down(lsq, o);
    }
    int wid = tid >> 6, lane = tid & 63;
    if (lane == 0) { ssum[wid] = lsum; ssq[wid] = lsq; }
    __syncthreads();
    if (tid == 0) {
        float s = 0.f, q = 0.f;
#pragma unroll
        for (int i = 0; i < 4; i++) { s += ssum[i]; q += ssq[i]; }
        float mu = s / CC;
        float var = q / CC - mu * mu;
        ssum[0] = mu;
        ssq[0] = rsqrtf(var + 1e-5f);
    }
    __syncthreads();
    float mu = ssum[0], rstd = ssq[0];
#pragma unroll
    for (int i = 0; i < 4; i++) {
        int c = tid + 256 * i;
        orow[c] = f2bf((v[i] - mu) * rstd * g[c] + b[c]);
    }
}

// ---------------- bf16 MFMA GEMM: C[M,N] = A[M,K](bf16) @ Bt[N,K](bf16)^T + epilogue ------
// 512 threads = 8 waves (2M x 4N), each wave 64x32 of the 128x128 tile -> 16 waves/CU at
// 2 blocks/CU (doubles latency-hiding TLP for the small-N GEMMs whose grid is only 512).
// BK=32 double-buffered: tile k+1's global_load_lds issued BEFORE MFMA work on tile k.
// XOR swizzle: LDS slot (row,c) holds global chunk c ^ ((row>>1)&3), applied at the global
// source; readers use slot quad ^ ((ml>>1)&3) -> all LDS phases 2-way (free).
enum { EPI_BIAS_RES_F32 = 1, EPI_BIAS_GELU_BF16 = 2, EPI_QKV = 3 };

template <int EPI>
__global__ __launch_bounds__(512) void mgemm(const unsigned short* __restrict__ A,
                                             const unsigned short* __restrict__ Bt,
                                             const float* __restrict__ bias,
                                             const float* __restrict__ R,
                                             float* __restrict__ Cf,
                                             unsigned short* __restrict__ Cb,
                                             unsigned short* __restrict__ Vb,
                                             int M, int N, int K) {
    __shared__ __align__(16) unsigned short As[2][128 * 32];
    __shared__ __align__(16) unsigned short Bs[2][128 * 32];
    int tid = threadIdx.x;
    int w = tid >> 6, lane = tid & 63;
    int bm = blockIdx.y * 128, bn = blockIdx.x * 128;
    int wr = (w >> 2) * 64, wc = (w & 3) * 32;

    // staging: thread covers ONE 16B slot: row = tid>>2, chunk slot tid&3 holds global
    // chunk (tid&3) ^ ((tid>>3)&3). Wave w writes LDS [w*1024, w*1024+1024).
    int kswz = ((tid & 3) ^ ((tid >> 3) & 3)) * 8;
    const unsigned short* gA = A + (size_t)(bm + (tid >> 2)) * K + kswz;
    const unsigned short* gB = Bt + (size_t)(bn + (tid >> 2)) * K + kswz;

    int ml = lane & 15, quad = lane >> 4;
    int rswz = quad ^ ((ml >> 1) & 3);

    f32x4 acc[4][2] = {};

#define STAGE(buf, k0)                                                  \
    do {                                                                \
        gload_lds16(gA + (k0), (char*)As[buf] + w * 1024);              \
        gload_lds16(gB + (k0), (char*)Bs[buf] + w * 1024);              \
    } while (0)

#define COMPUTE(buf)                                                    \
    do {                                                                \
        const bf16x8* pa = (const bf16x8*)As[buf] + (wr + ml) * 4 + rswz; \
        const bf16x8* pb = (const bf16x8*)Bs[buf] + (wc + ml) * 4 + rswz; \
        bf16x8 a[4], bb[2];                                             \
        _Pragma("unroll")                                               \
        for (int ti = 0; ti < 4; ti++) a[ti] = pa[ti * 64];             \
        _Pragma("unroll")                                               \
        for (int tj = 0; tj < 2; tj++) bb[tj] = pb[tj * 64];            \
        _Pragma("unroll")                                               \
        for (int ti = 0; ti < 4; ti++)                                  \
            _Pragma("unroll")                                           \
            for (int tj = 0; tj < 2; tj++)                              \
                acc[ti][tj] = __builtin_amdgcn_mfma_f32_16x16x32_bf16(  \
                    a[ti], bb[tj], acc[ti][tj], 0, 0, 0);               \
    } while (0)

    STAGE(0, 0);
    __syncthreads();
    for (int k0 = 0; k0 < K; k0 += 64) {        // K % 64 == 0 always here
        if (k0 + 32 < K) STAGE(1, k0 + 32);
        COMPUTE(0);
        __syncthreads();
        if (k0 + 64 < K) STAGE(0, k0 + 64);
        COMPUTE(1);
        __syncthreads();
    }
#undef STAGE
#undef COMPUTE

    // epilogue: D[m][n]: n = lane&15 (col), m = quad*4 + reg
#pragma unroll
    for (int ti = 0; ti < 4; ti++) {
#pragma unroll
        for (int tj = 0; tj < 2; tj++) {
            int n = bn + wc + tj * 16 + ml;
            int mbase = bm + wr + ti * 16 + quad * 4;
            float bv = bias[n];
            if (EPI == EPI_QKV && n >= 2 * CC) {
                // V: write transposed per-head: vt[b][h][d][t], t=mbase..+3 contiguous
                int d = n & (HD - 1), hh = (n - 2 * CC) >> 6;
                int tok = mbase & (TT - 1), bi = mbase >> 9;
                ushort4 pk;
                pk.x = f2bf(acc[ti][tj][0] + bv);
                pk.y = f2bf(acc[ti][tj][1] + bv);
                pk.z = f2bf(acc[ti][tj][2] + bv);
                pk.w = f2bf(acc[ti][tj][3] + bv);
                *(ushort4*)&Vb[((size_t)(bi * HH + hh) * HD + d) * TT + tok] = pk;
            } else {
#pragma unroll
                for (int reg = 0; reg < 4; reg++) {
                    int m = mbase + reg;
                    float v = acc[ti][tj][reg] + bv;
                    if (EPI == EPI_BIAS_GELU_BF16) {
                        // gelu(v) = v * sigmoid(2u)
                        float u2 = 1.5957691216057308f * (v + 0.044715f * v * v * v);
                        v = v / (1.0f + __expf(-u2));
                        Cb[(size_t)m * N + n] = f2bf(v);
                    } else if (EPI == EPI_QKV) {
                        Cb[(size_t)m * N + n] = f2bf(v);   // Q,K region
                    } else {  // EPI_BIAS_RES_F32
                        v += R[(size_t)m * N + n];
                        Cf[(size_t)m * N + n] = v;
                    }
                }
            }
        }
    }
}

// ---------------- MFMA flash attention: block = (b,h,64-query tile), 4 waves x 16 q ------
// qkvb [B*T][3C] bf16 (Q at h*64, K at C+h*64); vt [B][H][HD][T] bf16; out yb [B*T][C] bf16
__global__ __launch_bounds__(256) void attn_kernel(const unsigned short* __restrict__ qkvb,
                                                   const unsigned short* __restrict__ vt,
                                                   const int* __restrict__ mask,
                                                   unsigned short* __restrict__ yb) {
    __shared__ __align__(16) unsigned short Qs[64][72];
    __shared__ __align__(16) unsigned short Ks[64][72];
    __shared__ __align__(16) unsigned short Vs[64][72];   // Vs[d][key]
    __shared__ __align__(16) unsigned short Ps[4][16][72];
    __shared__ int ms[64];
    int qt = blockIdx.x, h = blockIdx.y, b = blockIdx.z;
    int tid = threadIdx.x;
    int w = tid >> 6, lane = tid & 63, ml = lane & 15, quad = lane >> 4;

    const size_t row3 = 3 * CC;
    const unsigned short* qbase = qkvb + (size_t)(b * TT + qt * 64) * row3 + h * HD;
    const unsigned short* kbase = qkvb + (size_t)(b * TT) * row3 + CC + h * HD;
    const unsigned short* vbase = vt + (size_t)(b * HH + h) * HD * TT;

    // stage Q once: 64 rows x 8 chunks of 8 bf16
#pragma unroll
    for (int i = 0; i < 2; i++) {
        int c = i * 256 + tid; int r = c >> 3, c8 = c & 7;
        *(uint4*)&Qs[r][c8 * 8] = *(const uint4*)(qbase + (size_t)r * row3 + c8 * 8);
    }

    f32x4 o[4] = {};           // o[tj][reg]: row=quad*4+reg, col(d)=tj*16+ml
    float m_i[4], l_i[4];
#pragma unroll
    for (int r = 0; r < 4; r++) { m_i[r] = -1e30f; l_i[r] = 0.f; }

    for (int k0 = 0; k0 < TT; k0 += 64) {
#pragma unroll
        for (int i = 0; i < 2; i++) {
            int c = i * 256 + tid; int r = c >> 3, c8 = c & 7;
            *(uint4*)&Ks[r][c8 * 8] = *(const uint4*)(kbase + (size_t)(k0 + r) * row3 + c8 * 8);
            *(uint4*)&Vs[r][c8 * 8] = *(const uint4*)(vbase + (size_t)r * TT + k0 + c8 * 8);
        }
        if (tid < 64) ms[tid] = mask[b * TT + k0 + tid];
        __syncthreads();

        // S = Q K^T  (16q x 64keys per wave)
        bf16x8 aq0 = *(const bf16x8*)&Qs[w * 16 + ml][quad * 8];
        bf16x8 aq1 = *(const bf16x8*)&Qs[w * 16 + ml][32 + quad * 8];
        float p[4][4];
        float mt[4] = {-1e30f, -1e30f, -1e30f, -1e30f};
#pragma unroll
        for (int tj = 0; tj < 4; tj++) {
            bf16x8 b0 = *(const bf16x8*)&Ks[tj * 16 + ml][quad * 8];
            bf16x8 b1 = *(const bf16x8*)&Ks[tj * 16 + ml][32 + quad * 8];
            f32x4 z = {};
            z = __builtin_amdgcn_mfma_f32_16x16x32_bf16(aq0, b0, z, 0, 0, 0);
            z = __builtin_amdgcn_mfma_f32_16x16x32_bf16(aq1, b1, z, 0, 0, 0);
            bool dead = (ms[tj * 16 + ml] == 0);
#pragma unroll
            for (int r = 0; r < 4; r++) {
                float v = dead ? -1e30f : z[r] * 0.125f;
                p[tj][r] = v;
                mt[r] = fmaxf(mt[r], v);
            }
        }
#pragma unroll
        for (int off = 1; off < 16; off <<= 1)
#pragma unroll
            for (int r = 0; r < 4; r++) mt[r] = fmaxf(mt[r], __shfl_xor(mt[r], off));
        float alpha[4], rs[4];
#pragma unroll
        for (int r = 0; r < 4; r++) {
            float mn = fmaxf(m_i[r], mt[r]);
            alpha[r] = __expf(m_i[r] - mn);
            m_i[r] = mn;
            rs[r] = 0.f;
#pragma unroll
            for (int tj = 0; tj < 4; tj++) {
                float e = __expf(p[tj][r] - mn);
                p[tj][r] = e;
                rs[r] += e;
            }
        }
#pragma unroll
        for (int off = 1; off < 16; off <<= 1)
#pragma unroll
            for (int r = 0; r < 4; r++) rs[r] += __shfl_xor(rs[r], off);
#pragma unroll
        for (int r = 0; r < 4; r++) {
            l_i[r] = l_i[r] * alpha[r] + rs[r];
#pragma unroll
            for (int tj = 0; tj < 4; tj++) o[tj][r] *= alpha[r];
        }
        // P (C-layout) -> LDS bf16 -> A-layout frags  (wave-private strip, no barrier)
#pragma unroll
        for (int tj = 0; tj < 4; tj++)
#pragma unroll
            for (int r = 0; r < 4; r++)
                Ps[w][quad * 4 + r][tj * 16 + ml] = f2bf(p[tj][r]);
        bf16x8 pa0 = *(const bf16x8*)&Ps[w][ml][quad * 8];
        bf16x8 pa1 = *(const bf16x8*)&Ps[w][ml][32 + quad * 8];
#pragma unroll
        for (int tj = 0; tj < 4; tj++) {
            bf16x8 v0 = *(const bf16x8*)&Vs[tj * 16 + ml][quad * 8];
            bf16x8 v1 = *(const bf16x8*)&Vs[tj * 16 + ml][32 + quad * 8];
            o[tj] = __builtin_amdgcn_mfma_f32_16x16x32_bf16(pa0, v0, o[tj], 0, 0, 0);
            o[tj] = __builtin_amdgcn_mfma_f32_16x16x32_bf16(pa1, v1, o[tj], 0, 0, 0);
        }
        __syncthreads();
    }

    // epilogue: q = qt*64 + w*16 + quad*4+r, d = tj*16+ml
#pragma unroll
    for (int r = 0; r < 4; r++) {
        float inv = 1.f / l_i[r];
        int q = qt * 64 + w * 16 + quad * 4 + r;
        unsigned short* yr = yb + (size_t)(b * TT + q) * CC + h * HD;
#pragma unroll
        for (int tj = 0; tj < 4; tj++)
            yr[tj * 16 + ml] = f2bf(o[tj][r] * inv);
    }
}

extern "C" void kernel_launch(void* const* d_in, const int* in_sizes, int n_in,
                              void* d_out, int out_size, void* d_ws, size_t ws_size,
                              hipStream_t stream) {
    const float* x      = (const float*)d_in[0];
    const int*   mask   = (const int*)d_in[1];
    const float* ln1_g  = (const float*)d_in[2];
    const float* ln1_b  = (const float*)d_in[3];
    const float* w_attn = (const float*)d_in[4];
    const float* b_attn = (const float*)d_in[5];
    const float* w_o    = (const float*)d_in[6];
    const float* b_o    = (const float*)d_in[7];
    const float* ln2_g  = (const float*)d_in[8];
    const float* ln2_b  = (const float*)d_in[9];
    const float* w_fc   = (const float*)d_in[10];
    const float* b_fc   = (const float*)d_in[11];
    const float* w_fc2  = (const float*)d_in[12];
    const float* b_fc2  = (const float*)d_in[13];
    float* out = (float*)d_out;

    char* ws = (char*)d_ws;
    size_t off = 0;
    unsigned short* wt_attn = (unsigned short*)(ws + off); off += (size_t)3 * CC * CC * 2;  // 6MB
    unsigned short* wt_o    = (unsigned short*)(ws + off); off += (size_t)CC * CC * 2;      // 2MB
    unsigned short* wt_fc   = (unsigned short*)(ws + off); off += (size_t)4 * CC * CC * 2;  // 8MB
    unsigned short* wt_fc2  = (unsigned short*)(ws + off); off += (size_t)4 * CC * CC * 2;  // 8MB
    // region1 (64MB): qkvb(48) + vt(16), reused as act(64) after attention
    unsigned short* qkvb    = (unsigned short*)(ws + off);
    unsigned short* act     = (unsigned short*)(ws + off); off += (size_t)NT * 3 * CC * 2;
    unsigned short* vt      = (unsigned short*)(ws + off); off += (size_t)BB * CC * TT * 2; // B*H*HD*T
    unsigned short* hb      = (unsigned short*)(ws + off);                                   // 16MB, reused as yb
    unsigned short* yb      = (unsigned short*)(ws + off); off += (size_t)NT * CC * 2;
    float* x1               = (float*)(ws + off); off += (size_t)NT * CC * 4;                // 32MB
    unsigned short* h2b     = (unsigned short*)(ws + off); off += (size_t)NT * CC * 2;       // 16MB

    // weight transpose+convert: W[K,N] f32 -> Wt[N,K] bf16
    tcvt_kernel<<<dim3(3 * CC / 32, CC / 32), 256, 0, stream>>>(w_attn, wt_attn, CC, 3 * CC);
    tcvt_kernel<<<dim3(CC / 32, CC / 32), 256, 0, stream>>>(w_o, wt_o, CC, CC);
    tcvt_kernel<<<dim3(4 * CC / 32, CC / 32), 256, 0, stream>>>(w_fc, wt_fc, CC, 4 * CC);
    tcvt_kernel<<<dim3(CC / 32, 4 * CC / 32), 256, 0, stream>>>(w_fc2, wt_fc2, 4 * CC, CC);

    // 1. LN1 -> bf16
    ln_kernel<<<NT, 256, 0, stream>>>(x, ln1_g, ln1_b, hb);
    // 2. qkv GEMM -> Q,K bf16 [B*T,3C] + V transposed vt[b][h][d][t]
    mgemm<EPI_QKV><<<dim3(3 * CC / 128, NT / 128), 512, 0, stream>>>(
        hb, wt_attn, b_attn, nullptr, nullptr, qkvb, vt, NT, 3 * CC, CC);
    // 3. MFMA flash attention -> yb bf16
    attn_kernel<<<dim3(TT / 64, HH, BB), 256, 0, stream>>>(qkvb, vt, mask, yb);
    // 4. x1 = y @ w_o + b_o + x
    mgemm<EPI_BIAS_RES_F32><<<dim3(CC / 128, NT / 128), 512, 0, stream>>>(
        yb, wt_o, b_o, x, x1, nullptr, nullptr, NT, CC, CC);
    // 5. LN2 -> bf16
    ln_kernel<<<NT, 256, 0, stream>>>(x1, ln2_g, ln2_b, h2b);
    // 6. act = gelu(h2 @ w_fc + b_fc) -> bf16 (into region1; qkvb/vt dead)
    mgemm<EPI_BIAS_GELU_BF16><<<dim3(4 * CC / 128, NT / 128), 512, 0, stream>>>(
        h2b, wt_fc, b_fc, nullptr, nullptr, act, nullptr, NT, 4 * CC, CC);
    // 7. out = act @ w_fc2 + b_fc2 + x1
    mgemm<EPI_BIAS_RES_F32><<<dim3(CC / 128, NT / 128), 512, 0, stream>>>(
        act, wt_fc2, b_fc2, x1, out, nullptr, nullptr, NT, CC, 4 * CC);
}